// Round 1
// baseline (8139.179 us; speedup 1.0000x reference)
//
#include <hip/hip_runtime.h>

// MotilityModel: force = W2 @ relu(LN(W1 @ cs + b1)) + b2
// N=500000 cells, CS=64, H=256, S=3, fp32.
// Compute-bound on fp32 VALU (no fp32 MFMA on CDNA4): 17.2 GFLOP @ 157 TF ~ 109us floor.
// Design: W1 transposed in LDS (64KB, 2 blocks/CU), 4 cells/wave/iter,
// lane owns hidden 4l..4l+3 -> wave-local LN reductions, readlane cs broadcast.

#define CS_DIM 64
#define H_DIM 256
constexpr float LN_EPS = 1e-5f;

__device__ __forceinline__ float bcast_lane(float v, int srcLane) {
    return __int_as_float(__builtin_amdgcn_readlane(__float_as_int(v), srcLane));
}

__global__ __launch_bounds__(256, 2) void motility_kernel(
    const float* __restrict__ cs, const float* __restrict__ W1,
    const float* __restrict__ b1, const float* __restrict__ gamma,
    const float* __restrict__ beta, const float* __restrict__ W2,
    const float* __restrict__ b2, float* __restrict__ out, int n)
{
    __shared__ float w1t[64][256];   // 64 KB: W1 transposed [k][h]

    const int tid  = threadIdx.x;
    const int lane = tid & 63;
    const int wave = tid >> 6;
    const int h0   = 4 * lane;

    // ---- stage W1 transposed: wave w handles k in [16w, 16w+16) ----
    // ds_write_b128 covers full 1KB row per wave -> conflict-free.
#pragma unroll
    for (int kk = 0; kk < 16; ++kk) {
        const int k = wave * 16 + kk;
        float4 v;
        v.x = W1[(h0 + 0) * 64 + k];
        v.y = W1[(h0 + 1) * 64 + k];
        v.z = W1[(h0 + 2) * 64 + k];
        v.w = W1[(h0 + 3) * 64 + k];
        *reinterpret_cast<float4*>(&w1t[k][h0]) = v;
    }

    // ---- per-lane constants (hidden units h0..h0+3), all coalesced x4 loads ----
    float b1v[4], gv[4], bev[4], w20[4], w21[4], w22[4];
    {
        const float4 t0 = *reinterpret_cast<const float4*>(&b1[h0]);
        const float4 t1 = *reinterpret_cast<const float4*>(&gamma[h0]);
        const float4 t2 = *reinterpret_cast<const float4*>(&beta[h0]);
        const float4 t3 = *reinterpret_cast<const float4*>(&W2[0 * H_DIM + h0]);
        const float4 t4 = *reinterpret_cast<const float4*>(&W2[1 * H_DIM + h0]);
        const float4 t5 = *reinterpret_cast<const float4*>(&W2[2 * H_DIM + h0]);
        b1v[0]=t0.x; b1v[1]=t0.y; b1v[2]=t0.z; b1v[3]=t0.w;
        gv[0]=t1.x;  gv[1]=t1.y;  gv[2]=t1.z;  gv[3]=t1.w;
        bev[0]=t2.x; bev[1]=t2.y; bev[2]=t2.z; bev[3]=t2.w;
        w20[0]=t3.x; w20[1]=t3.y; w20[2]=t3.z; w20[3]=t3.w;
        w21[0]=t4.x; w21[1]=t4.y; w21[2]=t4.z; w21[3]=t4.w;
        w22[0]=t5.x; w22[1]=t5.y; w22[2]=t5.z; w22[3]=t5.w;
    }
    const float b2x = b2[0], b2y = b2[1], b2z = b2[2];

    __syncthreads();

    const int tiles = (n + 15) >> 4;   // 16 cells per block-iteration
    for (int tile = blockIdx.x; tile < tiles; tile += gridDim.x) {
        const int cell0 = tile * 16 + wave * 4;     // this wave's 4 cells
        if (cell0 >= n) continue;

        // lane l holds cs[cell0 + l/16][(l%16)*4 .. +3] : one coalesced 1KB load
        float cv[4];
        {
            const float4 t = *reinterpret_cast<const float4*>(
                &cs[(size_t)cell0 * CS_DIM + 4 * lane]);
            cv[0]=t.x; cv[1]=t.y; cv[2]=t.z; cv[3]=t.w;
        }

        float acc[4][4];
#pragma unroll
        for (int c = 0; c < 4; ++c)
#pragma unroll
            for (int j = 0; j < 4; ++j) acc[c][j] = b1v[j];

        // ---- GEMM1: h[c][h0+j] += sum_k W1t[k][h0+j] * cs[c][k] ----
#pragma unroll
        for (int k = 0; k < 64; ++k) {
            const float4 w4 = *reinterpret_cast<const float4*>(&w1t[k][h0]);
#pragma unroll
            for (int c = 0; c < 4; ++c) {
                // cs[cell0+c][k] lives in lane c*16 + k/4, component k%4
                const float bc = bcast_lane(cv[k & 3], c * 16 + (k >> 2));
                acc[c][0] = fmaf(w4.x, bc, acc[c][0]);
                acc[c][1] = fmaf(w4.y, bc, acc[c][1]);
                acc[c][2] = fmaf(w4.z, bc, acc[c][2]);
                acc[c][3] = fmaf(w4.w, bc, acc[c][3]);
            }
        }

        // ---- LayerNorm + ReLU + GEMM2, wave-local per cell ----
#pragma unroll
        for (int c = 0; c < 4; ++c) {
            float s1 = acc[c][0] + acc[c][1] + acc[c][2] + acc[c][3];
            float s2 = acc[c][0]*acc[c][0] + acc[c][1]*acc[c][1]
                     + acc[c][2]*acc[c][2] + acc[c][3]*acc[c][3];
#pragma unroll
            for (int m = 1; m < 64; m <<= 1) {
                s1 += __shfl_xor(s1, m);
                s2 += __shfl_xor(s2, m);
            }
            const float mu  = s1 * (1.0f / 256.0f);
            const float var = s2 * (1.0f / 256.0f) - mu * mu;
            const float rs  = rsqrtf(var + LN_EPS);

            float p0 = 0.f, p1 = 0.f, p2 = 0.f;
#pragma unroll
            for (int j = 0; j < 4; ++j) {
                float hn = (acc[c][j] - mu) * rs * gv[j] + bev[j];
                hn = fmaxf(hn, 0.0f);
                p0 = fmaf(hn, w20[j], p0);
                p1 = fmaf(hn, w21[j], p1);
                p2 = fmaf(hn, w22[j], p2);
            }
#pragma unroll
            for (int m = 1; m < 64; m <<= 1) {
                p0 += __shfl_xor(p0, m);
                p1 += __shfl_xor(p1, m);
                p2 += __shfl_xor(p2, m);
            }
            if (lane == 0) {
                const int cell = cell0 + c;
                if (cell < n) {
                    out[(size_t)cell * 3 + 0] = p0 + b2x;
                    out[(size_t)cell * 3 + 1] = p1 + b2y;
                    out[(size_t)cell * 3 + 2] = p2 + b2z;
                }
            }
        }
    }
}

extern "C" void kernel_launch(void* const* d_in, const int* in_sizes, int n_in,
                              void* d_out, int out_size, void* d_ws, size_t ws_size,
                              hipStream_t stream) {
    const float* cs    = (const float*)d_in[0];
    const float* W1    = (const float*)d_in[1];
    const float* b1    = (const float*)d_in[2];
    const float* gamma = (const float*)d_in[3];
    const float* beta  = (const float*)d_in[4];
    const float* W2    = (const float*)d_in[5];
    const float* b2    = (const float*)d_in[6];
    float* out = (float*)d_out;

    const int n = in_sizes[0] / CS_DIM;   // 500000

    // 2 blocks/CU (64KB LDS each) x 256 CU = 512 resident; grid-stride tiles.
    motility_kernel<<<dim3(512), dim3(256), 0, stream>>>(
        cs, W1, b1, gamma, beta, W2, b2, out, n);
}

// Round 2
// 423.329 us; speedup vs baseline: 19.2266x; 19.2266x over previous
//
#include <hip/hip_runtime.h>

// MotilityModel: force = W2 @ relu(LN(W1 @ cs + b1)) + b2
// N=500000, CS=64, H=256, S=3, fp32. No fp32 MFMA on CDNA4 -> VALU fma,
// compute floor ~109us @ 157 TF.
//
// R1 failure: rolled k-loop => cv[k&3]/acc runtime-indexed => scratch =>
// 28.5 GB HBM traffic, VALUBusy 5.8%. This version has NO private array
// with a loop-variable index: cs broadcasts come from uniform-address LDS
// reads (free broadcast, LDS pipe), acc[8][4] only static-indexed, and all
// wave reductions use VALU DPP butterflies (no ds_bpermute).

#define CS_DIM 64
#define H_DIM 256
constexpr float LN_EPS = 1e-5f;

template <int CTRL>
__device__ __forceinline__ float dpp_add(float x) {
    // x + dpp_move(x); bound_ctrl=1 (invalid source lanes contribute 0)
    int m = __builtin_amdgcn_update_dpp(0, __float_as_int(x), CTRL, 0xF, 0xF, true);
    return x + __int_as_float(m);
}

// Full 64-lane sum. Result valid in lanes 48..63 (read lane 63).
__device__ __forceinline__ float wave_sum64(float x) {
    x = dpp_add<0xB1>(x);    // quad_perm [1,0,3,2] : + (lane^1)
    x = dpp_add<0x4E>(x);    // quad_perm [2,3,0,1] : + (lane^2)
    x = dpp_add<0x141>(x);   // row_half_mirror     : 8-group sum
    x = dpp_add<0x140>(x);   // row_mirror          : 16-group sum
    x = dpp_add<0x142>(x);   // row_bcast15         : rows 1,3 += rows 0,2
    x = dpp_add<0x143>(x);   // row_bcast31         : rows 2,3 += (r0+r1)
    return x;
}

__device__ __forceinline__ float bcast63(float x) {
    return __int_as_float(__builtin_amdgcn_readlane(__float_as_int(x), 63));
}

__global__ __launch_bounds__(512, 4) void motility_kernel(
    const float* __restrict__ cs, const float* __restrict__ W1,
    const float* __restrict__ b1, const float* __restrict__ gamma,
    const float* __restrict__ beta, const float* __restrict__ W2,
    const float* __restrict__ b2, float* __restrict__ out, int n)
{
    __shared__ float w1t[64][256];   // 64 KB: W1 transposed [k][h]
    __shared__ float cst[8][512];    // 16 KB: per-wave 8 cells x 64 (linear)

    const int tid  = threadIdx.x;
    const int lane = tid & 63;
    const int wave = tid >> 6;       // 0..7
    const int h0   = 4 * lane;       // this lane's hidden units h0..h0+3

    // ---- stage W1^T: wave w covers k in [8w, 8w+8). Writes are full-row
    // b128 (conflict-free); reads are strided but W1 (64KB) is L2-hot.
#pragma unroll
    for (int kk = 0; kk < 8; ++kk) {
        const int k = wave * 8 + kk;
        float4 v;
        v.x = W1[(h0 + 0) * 64 + k];
        v.y = W1[(h0 + 1) * 64 + k];
        v.z = W1[(h0 + 2) * 64 + k];
        v.w = W1[(h0 + 3) * 64 + k];
        *reinterpret_cast<float4*>(&w1t[k][h0]) = v;
    }

    // ---- per-lane constants for hidden units h0..h0+3 (coalesced x4 loads)
    const float4 t0 = *reinterpret_cast<const float4*>(&b1[h0]);
    const float4 t1 = *reinterpret_cast<const float4*>(&gamma[h0]);
    const float4 t2 = *reinterpret_cast<const float4*>(&beta[h0]);
    const float4 t3 = *reinterpret_cast<const float4*>(&W2[0 * H_DIM + h0]);
    const float4 t4 = *reinterpret_cast<const float4*>(&W2[1 * H_DIM + h0]);
    const float4 t5 = *reinterpret_cast<const float4*>(&W2[2 * H_DIM + h0]);
    const float b2x = b2[0], b2y = b2[1], b2z = b2[2];

    __syncthreads();

    const int tiles = (n + 63) >> 6;            // 64 cells per block-tile
    for (int tile = blockIdx.x; tile < tiles; tile += gridDim.x) {
        const int cell0 = tile * 64 + wave * 8; // this wave's 8 cells
        if (cell0 >= n) continue;               // n%8==0: wave all-valid or skip

        // ---- stage 8 cells (2 KB) into this wave's LDS slab, linear layout.
        {
            const float4* src = reinterpret_cast<const float4*>(cs);
            long i0   = (long)cell0 * 16 + lane;     // float4 index
            long imax = (long)n * 16 - 1;            // clamp (defensive)
            long ia = i0 > imax ? imax : i0;
            long ib = (i0 + 64) > imax ? imax : (i0 + 64);
            const float4 a = src[ia];
            const float4 b = src[ib];
            float4* dst = reinterpret_cast<float4*>(cst[wave]);
            dst[lane]      = a;
            dst[lane + 64] = b;
            // wave-local RAW on LDS: compiler inserts lgkmcnt wait; no barrier
        }

        // ---- GEMM1: acc[c][j] = b1[h0+j] + sum_k w1t[k][h0+j] * cs[c][k]
        float acc[8][4];
#pragma unroll
        for (int c = 0; c < 8; ++c) {
            acc[c][0] = t0.x; acc[c][1] = t0.y;
            acc[c][2] = t0.z; acc[c][3] = t0.w;
        }

#pragma unroll 2
        for (int k2 = 0; k2 < 32; ++k2) {
            const float4 wA = *reinterpret_cast<const float4*>(&w1t[2 * k2][h0]);
            const float4 wB = *reinterpret_cast<const float4*>(&w1t[2 * k2 + 1][h0]);
#pragma unroll
            for (int c = 0; c < 8; ++c) {
                // uniform-address LDS read -> free broadcast to all lanes
                const float2 cp = *reinterpret_cast<const float2*>(
                    &cst[wave][c * 64 + 2 * k2]);
                acc[c][0] = fmaf(wA.x, cp.x, acc[c][0]);
                acc[c][1] = fmaf(wA.y, cp.x, acc[c][1]);
                acc[c][2] = fmaf(wA.z, cp.x, acc[c][2]);
                acc[c][3] = fmaf(wA.w, cp.x, acc[c][3]);
                acc[c][0] = fmaf(wB.x, cp.y, acc[c][0]);
                acc[c][1] = fmaf(wB.y, cp.y, acc[c][1]);
                acc[c][2] = fmaf(wB.z, cp.y, acc[c][2]);
                acc[c][3] = fmaf(wB.w, cp.y, acc[c][3]);
            }
        }

        // ---- LayerNorm + ReLU + GEMM2 per cell; reductions on VALU (DPP)
#pragma unroll
        for (int c = 0; c < 8; ++c) {
            const float a0 = acc[c][0], a1 = acc[c][1];
            const float a2 = acc[c][2], a3 = acc[c][3];
            float s1 = (a0 + a1) + (a2 + a3);
            float s2 = fmaf(a0, a0, fmaf(a1, a1, fmaf(a2, a2, a3 * a3)));
            s1 = wave_sum64(s1);
            s2 = wave_sum64(s2);
            const float S1 = bcast63(s1);
            const float S2 = bcast63(s2);
            const float mu  = S1 * (1.0f / 256.0f);
            const float var = fmaf(-mu, mu, S2 * (1.0f / 256.0f));
            const float rs  = rsqrtf(var + LN_EPS);

            float p0 = 0.f, p1 = 0.f, p2 = 0.f;
            {
                // j unrolled by hand; scale/offset folding: hn = a*sc + off
                const float sc0 = rs * t1.x, off0 = fmaf(-mu, sc0, t2.x);
                const float sc1 = rs * t1.y, off1 = fmaf(-mu, sc1, t2.y);
                const float sc2 = rs * t1.z, off2 = fmaf(-mu, sc2, t2.z);
                const float sc3 = rs * t1.w, off3 = fmaf(-mu, sc3, t2.w);
                float h;
                h = fmaxf(fmaf(a0, sc0, off0), 0.f);
                p0 = fmaf(h, t3.x, p0); p1 = fmaf(h, t4.x, p1); p2 = fmaf(h, t5.x, p2);
                h = fmaxf(fmaf(a1, sc1, off1), 0.f);
                p0 = fmaf(h, t3.y, p0); p1 = fmaf(h, t4.y, p1); p2 = fmaf(h, t5.y, p2);
                h = fmaxf(fmaf(a2, sc2, off2), 0.f);
                p0 = fmaf(h, t3.z, p0); p1 = fmaf(h, t4.z, p1); p2 = fmaf(h, t5.z, p2);
                h = fmaxf(fmaf(a3, sc3, off3), 0.f);
                p0 = fmaf(h, t3.w, p0); p1 = fmaf(h, t4.w, p1); p2 = fmaf(h, t5.w, p2);
            }
            p0 = wave_sum64(p0);
            p1 = wave_sum64(p1);
            p2 = wave_sum64(p2);
            if (lane == 63) {
                const int cell = cell0 + c;
                if (cell < n) {
                    out[(size_t)cell * 3 + 0] = p0 + b2x;
                    out[(size_t)cell * 3 + 1] = p1 + b2y;
                    out[(size_t)cell * 3 + 2] = p2 + b2z;
                }
            }
        }
    }
}

extern "C" void kernel_launch(void* const* d_in, const int* in_sizes, int n_in,
                              void* d_out, int out_size, void* d_ws, size_t ws_size,
                              hipStream_t stream) {
    const float* cs    = (const float*)d_in[0];
    const float* W1    = (const float*)d_in[1];
    const float* b1    = (const float*)d_in[2];
    const float* gamma = (const float*)d_in[3];
    const float* beta  = (const float*)d_in[4];
    const float* W2    = (const float*)d_in[5];
    const float* b2    = (const float*)d_in[6];
    float* out = (float*)d_out;

    const int n = in_sizes[0] / CS_DIM;   // 500000

    // 80 KB LDS/block -> 2 blocks/CU; 512 blocks = exactly resident.
    motility_kernel<<<dim3(512), dim3(512), 0, stream>>>(
        cs, W1, b1, gamma, beta, W2, b2, out, n);
}